// Round 10
// baseline (422.271 us; speedup 1.0000x reference)
//
#include <hip/hip_runtime.h>

// CRF loss: mean_b( logZ(b) - gold(b) )   B=2048, T=512, K=25
// R10: MFMA-batched linear-domain forward. 32 batches per wave:
//   alpha_next(32x32) = E_t ∘ (expT(32x32,bf16) · alpha(32x32,bf16))
// via 2x v_mfma_f32_32x32x16_bf16 per step. C->B fragment relayout via
// 4x v_permlane32_swap_b32 + 8x v_cvt_pk_bf16_f32 (no LDS). Per-column
// freeze (cndmask) + exact pow2 rescale every 4 steps. Gold path fused
// as 2048 independent 1-wave blocks (L3-hit gathers).

#define BB 2048
#define TT 512
#define KK 25
#define START_S 23
#define STOP_S 24
#define LOG2E 1.4426950408889634f
#define LN2   0.6931471805599453f
#define NFWD 64                       // 2048 / 32 batch-groups

typedef __attribute__((ext_vector_type(8)))  short bf16x8;
typedef __attribute__((ext_vector_type(16))) float f32x16;

static __device__ __forceinline__ float fexp2(float x){ return __builtin_amdgcn_exp2f(x); }
static __device__ __forceinline__ float flog2(float x){ return __builtin_amdgcn_logf(x); }

static __device__ __forceinline__ unsigned cvtpk(float lo, float hi){
    unsigned d;
    asm("v_cvt_pk_bf16_f32 %0, %1, %2" : "=v"(d) : "v"(lo), "v"(hi));
    return d;
}
static __device__ __forceinline__ void swap32(unsigned &a, unsigned &b){
    asm("v_permlane32_swap_b32 %0, %1" : "+v"(a), "+v"(b));
}
static __device__ __forceinline__ unsigned short f2bf_rne(float x){
    unsigned u = __float_as_uint(x);
    u += 0x7FFFu + ((u >> 16) & 1u);
    return (unsigned short)(u >> 16);
}

__global__ __launch_bounds__(64, 1) void crf_fused_kernel(
    const float* __restrict__ feats,      // [B][T][K]
    const int*   __restrict__ tags,       // [B][T]
    const int*   __restrict__ lengths,    // [B]
    const float* __restrict__ trans,      // [K][K]
    float*       __restrict__ out)        // [1]
{
    __shared__ float tlds[KK * KK];
    const int lane = threadIdx.x;
    for (int i = lane; i < KK * KK; i += 64) tlds[i] = trans[i];
    __syncthreads();

    if (blockIdx.x >= NFWD) {
        // ================= gold block: one wave per batch =================
        const int b   = blockIdx.x - NFWD;
        const int len = lengths[b];
        const int*   tb  = tags  + (size_t)b * TT;
        const float* fbb = feats + (size_t)b * TT * KK;
        float g = 0.f;
        #pragma unroll
        for (int it = 0; it < 8; ++it) {
            const int t  = it * 64 + lane;
            const int tg = tb[t];
            const int tp = (t == 0) ? START_S : tb[t - 1];
            if (t < len)       g += fbb[t * KK + tg] + tlds[tg * KK + tp];
            if (t == len - 1)  g += tlds[STOP_S * KK + tg];
        }
        g += __shfl_xor(g, 32); g += __shfl_xor(g, 16); g += __shfl_xor(g, 8);
        g += __shfl_xor(g, 4);  g += __shfl_xor(g, 2);  g += __shfl_xor(g, 1);
        if (lane == 0) atomicAdd(out, -g * (1.0f / BB));
        return;
    }

    // ================= forward block: 32 batches per wave =================
    const int n  = lane & 31;          // batch column
    const int h  = lane >> 5;          // lane half
    const int b0 = blockIdx.x * 32;
    const int len_n = lengths[b0 + n];

    int lm = len_n;
    lm = max(lm, __shfl_xor(lm, 16)); lm = max(lm, __shfl_xor(lm, 8));
    lm = max(lm, __shfl_xor(lm, 4));  lm = max(lm, __shfl_xor(lm, 2));
    lm = max(lm, __shfl_xor(lm, 1));
    const int lmax  = __builtin_amdgcn_readfirstlane(lm);
    const int niter = (lmax + 7) >> 3;

    // ---- A-fragments: expT bf16 (static). A[row][k]: row=lane%32, k=h*8+e (+16 half1)
    union { unsigned short s[8]; bf16x8 v; } A0, A1;
    #pragma unroll
    for (int e = 0; e < 8; ++e) {
        const int k = h * 8 + e;
        float v0 = 0.f, v1 = 0.f;
        if (n < KK) {                                  // row = n (lane%32)
            v0 = fexp2(tlds[n * KK + k] * LOG2E);      // k <= 15 < 25 always
            if (16 + k < KK) v1 = fexp2(tlds[n * KK + 16 + k] * LOG2E);
        }
        A0.s[e] = f2bf_rne(v0);
        A1.s[e] = f2bf_rne(v1);
    }

    // ---- per-lane C-fragment slots (regs 0..12): row = (s&3)+8*(s>>2)+4h
    int   idx[13]; float esC[13];
    #pragma unroll
    for (int s = 0; s < 13; ++s) {
        const int r = (s & 3) + 8 * (s >> 2) + 4 * h;
        idx[s] = n * TT * KK + r;
        esC[s] = (r < KK) ? fexp2(tlds[STOP_S * KK + r] * LOG2E) : 0.f;
    }

    float al[13];
    #pragma unroll
    for (int s = 0; s < 13; ++s) al[s] = 0.f;
    if (h == 1) al[11] = 1.f;          // row 23 = START (reg 11 on upper half)

    int   c2 = 0;
    const float* fbg = feats + (size_t)b0 * TT * KK;
    const f32x16 czero = {0,0,0,0,0,0,0,0,0,0,0,0,0,0,0,0};

    union { unsigned u[4]; bf16x8 v; } B0, B1;

#define PACK_B()                                                              \
    {                                                                         \
        unsigned dA0 = cvtpk(al[0], al[1]),   dA1 = cvtpk(al[2], al[3]);      \
        unsigned dB0 = cvtpk(al[4], al[5]),   dB1 = cvtpk(al[6], al[7]);      \
        unsigned dC0 = cvtpk(al[8], al[9]),   dC1 = cvtpk(al[10], al[11]);    \
        unsigned dD0 = cvtpk(al[12], 0.0f),   dD1 = 0u;                       \
        swap32(dA0, dB0); swap32(dA1, dB1);                                   \
        swap32(dC0, dD0); swap32(dC1, dD1);                                   \
        B0.u[0] = dA0; B0.u[1] = dA1; B0.u[2] = dB0; B0.u[3] = dB1;           \
        B1.u[0] = dC0; B1.u[1] = dC1; B1.u[2] = dD0; B1.u[3] = dD1;           \
    }

    PACK_B()   // initial B from alpha0

#define STEP(FS, TCUR, DORESC)                                                \
    {                                                                         \
        float E[13];                                                          \
        _Pragma("unroll") for (int s = 0; s < 12; ++s)                        \
            E[s] = fexp2(FS[s] * LOG2E);                                      \
        E[12] = h ? 0.f : fexp2(FS[12] * LOG2E);                              \
        f32x16 c = __builtin_amdgcn_mfma_f32_32x32x16_bf16(A0.v, B0.v, czero, 0, 0, 0); \
        c = __builtin_amdgcn_mfma_f32_32x32x16_bf16(A1.v, B1.v, c, 0, 0, 0);  \
        const bool act = (TCUR) < len_n;                                      \
        _Pragma("unroll") for (int s = 0; s < 13; ++s)                        \
            al[s] = act ? c[s] * E[s] : al[s];                                \
        if (DORESC) {                                                         \
            float f0 = fmaxf(al[0], al[1]),  f1 = fmaxf(al[2], al[3]);        \
            float f2 = fmaxf(al[4], al[5]),  f3 = fmaxf(al[6], al[7]);        \
            float f4 = fmaxf(al[8], al[9]),  f5 = fmaxf(al[10], al[11]);      \
            f0 = fmaxf(f0, f1); f2 = fmaxf(f2, f3); f4 = fmaxf(f4, f5);       \
            f0 = fmaxf(f0, f2); f4 = fmaxf(f4, al[12]);                       \
            float mx = fmaxf(f0, f4);                                         \
            mx = fmaxf(mx, __shfl_xor(mx, 32));                               \
            const int   e  = (int)(__float_as_uint(mx) >> 23) - 127;          \
            const float sc = __uint_as_float((unsigned)(127 - e) << 23);      \
            _Pragma("unroll") for (int s = 0; s < 13; ++s) al[s] *= sc;       \
            c2 += e;                                                          \
        }                                                                     \
        PACK_B()                                                              \
    }

#define LOADQ(DST, TQ)                                                        \
    {                                                                         \
        _Pragma("unroll") for (int s = 0; s < 12; ++s)                        \
            DST[s] = fbg[idx[s] + (TQ) * KK];                                 \
        DST[12] = h ? 0.f : fbg[idx[12] + (TQ) * KK];                         \
    }

    float P0[13], P1[13], P2[13], P3[13];
    float Q0[13], Q1[13], Q2[13], Q3[13];

    int t = 0;
    LOADQ(P0, 0) LOADQ(P1, 1) LOADQ(P2, 2) LOADQ(P3, 3)

    for (int it = 0; it < niter; ++it) {
        LOADQ(Q0, min(t + 4, TT - 1)) LOADQ(Q1, min(t + 5, TT - 1))
        LOADQ(Q2, min(t + 6, TT - 1)) LOADQ(Q3, min(t + 7, TT - 1))
        STEP(P0, t + 0, 0) STEP(P1, t + 1, 0) STEP(P2, t + 2, 0) STEP(P3, t + 3, 1)
        LOADQ(P0, min(t + 8,  TT - 1)) LOADQ(P1, min(t + 9,  TT - 1))
        LOADQ(P2, min(t + 10, TT - 1)) LOADQ(P3, min(t + 11, TT - 1))
        STEP(Q0, t + 4, 0) STEP(Q1, t + 5, 0) STEP(Q2, t + 6, 0) STEP(Q3, t + 7, 1)
        t += 8;
    }

#undef LOADQ
#undef STEP
#undef PACK_B

    // fwd_n = ln( sum_i alpha[i][n] * exp(T[STOP][i]) ) + c2_n * ln2
    float w = 0.f;
    #pragma unroll
    for (int s = 0; s < 13; ++s) w = fmaf(al[s], esC[s], w);
    w += __shfl_xor(w, 32);                       // combine lane pair (both halves same col)
    const float logZ = (flog2(w) + (float)c2) * LN2;
    float val = (lane < 32) ? logZ : 0.f;         // count each batch once
    val += __shfl_xor(val, 32); val += __shfl_xor(val, 16); val += __shfl_xor(val, 8);
    val += __shfl_xor(val, 4);  val += __shfl_xor(val, 2);  val += __shfl_xor(val, 1);
    if (lane == 0) atomicAdd(out, val * (1.0f / BB));
}

extern "C" void kernel_launch(void* const* d_in, const int* in_sizes, int n_in,
                              void* d_out, int out_size, void* d_ws, size_t ws_size,
                              hipStream_t stream) {
    const float* feats   = (const float*)d_in[0];
    const int*   tags    = (const int*)d_in[1];
    const int*   lengths = (const int*)d_in[2];
    const float* trans   = (const float*)d_in[3];
    float* out = (float*)d_out;

    (void)hipMemsetAsync(out, 0, sizeof(float), stream);
    crf_fused_kernel<<<NFWD + BB, 64, 0, stream>>>(feats, tags, lengths, trans, out);
}